// Round 2
// baseline (4952.703 us; speedup 1.0000x reference)
//
#include <hip/hip_runtime.h>
#include <hip/hip_cooperative_groups.h>

namespace cg = cooperative_groups;

#define NB_ 5   // N_BASIS
#define MD_ 5   // MAX_DELAY

// One persistent cooperative kernel runs the whole T-step simulation.
//  - thread tid < N owns neuron tid; all its state/constants live in registers
//  - spikes stored bit-packed: zbits[(T+MD) slots][words32 u32], slot u+MD = step u
//  - edge phase: dense scan of precomputed offs, gathering spike bits from an
//    LDS-staged 5-slot window; skipped entirely when window spike count == 0
//  - 2 grid syncs per step (edge->neuron, neuron->next edge)
__global__ __launch_bounds__(256, 2) void v1_persistent(
    const float* __restrict__ weights,
    const float* __restrict__ edge_basis,
    const float* __restrict__ ext_input,
    const float* __restrict__ decay_g,
    const float* __restrict__ cf_g,
    const float* __restrict__ g_g,
    const float* __restrict__ vth_g,
    const float* __restrict__ vrst_g,
    const float* __restrict__ nrm_g,
    const float* __restrict__ tref_g,
    const float* __restrict__ ek_g,      // (N,2)
    const float* __restrict__ am_g,      // (N,2)
    const float* __restrict__ sd_g,      // n5
    const float* __restrict__ pi_g,      // n5
    const int*   __restrict__ pre_idx,
    const int*   __restrict__ post_idx,
    float*       __restrict__ out,       // (T,N)
    int*         __restrict__ offs,      // ws: E
    float*       __restrict__ i_rec,     // ws: n5
    unsigned int* __restrict__ zbits,    // ws: (T+MD)*words32
    int*         __restrict__ scnt,      // ws: T+MD
    int N, int E, int T, int words32)
{
    extern __shared__ unsigned int zw_lds[];   // MD*words32 u32
    cg::grid_group grid = cg::this_grid();

    const int tid = blockIdx.x * blockDim.x + threadIdx.x;
    const int nth = gridDim.x * blockDim.x;
    const int n5  = N * NB_;
    const int bitstride = words32 * 32;
    const int wwords = words32 * MD_;

    // ---------------- setup (every launch: harness replays the graph) -------
    for (int i = tid; i < wwords; i += nth) zbits[i] = 0;          // slots 0..4
    for (int i = tid; i < n5; i += nth) i_rec[i] = 0.0f;
    for (int i = tid; i < T + MD_; i += nth) scnt[i] = 0;
    for (int e = tid; e < E; e += nth) {
        int pre = pre_idx[e];
        int d = pre / N;
        int n = pre - d * N;
        // bit address inside the sliding window coordinate system:
        // at step t, edge reads bit (t + MD-1-d)*bitstride + n  ==  t*bitstride + offs[e]
        offs[e] = (MD_ - 1 - d) * bitstride + n;
    }

    // ---------------- register-resident neuron state ------------------------
    const int  n   = tid;
    const bool has = (n < N);
    float v = 0.f, r = 0.f, a0 = 0.f, a1 = 0.f, pz = 0.f;
    float p[NB_] = {0.f, 0.f, 0.f, 0.f, 0.f};
    float dec = 0.f, cf = 0.f, gg = 0.f, vth = 0.f, vrst = 0.f, nrm = 0.f, tref = 0.f;
    float ek0 = 0.f, ek1 = 0.f, am0 = 0.f, am1 = 0.f;
    float sd[NB_], pi[NB_];
    #pragma unroll
    for (int k = 0; k < NB_; ++k) { sd[k] = 0.f; pi[k] = 0.f; }
    if (has) {
        dec = decay_g[n]; cf = cf_g[n]; gg = g_g[n];
        vth = vth_g[n]; vrst = vrst_g[n]; nrm = nrm_g[n]; tref = tref_g[n];
        ek0 = ek_g[2 * n]; ek1 = ek_g[2 * n + 1];
        am0 = am_g[2 * n]; am1 = am_g[2 * n + 1];
        #pragma unroll
        for (int k = 0; k < NB_; ++k) { sd[k] = sd_g[n * NB_ + k]; pi[k] = pi_g[n * NB_ + k]; }
        v = vrst;
    }

    grid.sync();   // offs/zbits/i_rec/scnt visible everywhere

    const int  E4    = E >> 2;
    const int4* offs4 = (const int4*)offs;

    for (int t = 0; t < T; ++t) {
        // ---- edge phase: accumulate i_rec from spikes in window [t, t+MD) ----
        int sc = 0;
        #pragma unroll
        for (int s = 0; s < MD_; ++s) sc += scnt[t + s];

        if (sc > 0) {
            const unsigned int* zw = zbits + (size_t)t * words32;
            for (int i = threadIdx.x; i < wwords; i += blockDim.x) zw_lds[i] = zw[i];
            __syncthreads();

            auto do_edge = [&](int off, int e) {
                if ((zw_lds[off >> 5] >> (off & 31)) & 1u) {
                    float wt = weights[e];
                    int   b  = post_idx[e] * NB_;
                    const float* bs = edge_basis + (size_t)e * NB_;
                    #pragma unroll
                    for (int k = 0; k < NB_; ++k)
                        atomicAdd(&i_rec[b + k], wt * bs[k]);
                }
            };
            for (int i = tid; i < E4; i += nth) {
                int4 o = offs4[i];
                int  e = i << 2;
                do_edge(o.x, e);
                do_edge(o.y, e + 1);
                do_edge(o.z, e + 2);
                do_edge(o.w, e + 3);
            }
            for (int e = (E4 << 2) + tid; e < E; e += nth) do_edge(offs[e], e);
        }
        grid.sync();   // i_rec complete

        // ---- neuron phase (registers; exact op order of the passing kernel) --
        float z = 0.0f;
        if (has) {
            const float* x  = ext_input + (size_t)t * n5 + n * NB_;
            float*       ir = i_rec + n * NB_;
            float ic = 0.0f;
            #pragma unroll
            for (int k = 0; k < NB_; ++k) {
                float pv = p[k] * sd[k] + (ir[k] + x[k]) * pi[k];
                p[k] = pv;
                ir[k] = 0.0f;            // clear for next step
                ic += pv;
            }
            a0 = ek0 * a0 + pz * am0;
            a1 = ek1 * a1 + pz * am1;
            float c1 = ic + (a0 + a1) + gg;
            float nv = dec * v + cf * c1;
            if (pz > 0.5f) nv = vrst;
            float vsc = (nv - vth) / nrm;
            z = (vsc > 0.0f) ? 1.0f : 0.0f;
            if (r > 0.0f) z = 0.0f;
            r = fmaxf(r + z * tref - 1.0f, 0.0f);   // DT = 1.0
            v = nv;
            pz = z;
            out[(size_t)t * N + n] = z;
        }
        // pack spikes of step t into zbits slot t+MD (wave ballot, 1 store/wave)
        unsigned long long m = __ballot(z != 0.0f);
        int wv = tid >> 6;
        if ((threadIdx.x & 63) == 0 && (wv << 6) < N) {
            *(unsigned long long*)(zbits + (size_t)(t + MD_) * words32 + (wv << 1)) = m;
            if (m) atomicAdd(&scnt[t + MD_], __popcll(m));
        }
        grid.sync();   // spikes of step t visible for edge phase t+1
    }
}

// ---------------------------------------------------------------------------
extern "C" void kernel_launch(void* const* d_in, const int* in_sizes, int n_in,
                              void* d_out, int out_size, void* d_ws, size_t ws_size,
                              hipStream_t stream)
{
    const float* weights        = (const float*)d_in[0];
    const float* edge_basis     = (const float*)d_in[1];
    const float* ext_input      = (const float*)d_in[2];
    const float* decay          = (const float*)d_in[3];
    const float* current_factor = (const float*)d_in[4];
    const float* gathered_g     = (const float*)d_in[5];
    const float* v_th           = (const float*)d_in[6];
    const float* v_reset        = (const float*)d_in[7];
    const float* normalizer     = (const float*)d_in[8];
    const float* t_ref          = (const float*)d_in[9];
    const float* exp_dt_k       = (const float*)d_in[10];
    const float* asc_amps       = (const float*)d_in[11];
    const float* syn_decay      = (const float*)d_in[12];
    const float* psc_initial    = (const float*)d_in[13];
    const int*   pre_idx        = (const int*)d_in[14];
    const int*   post_idx       = (const int*)d_in[15];

    const int E  = in_sizes[0];
    const int N  = in_sizes[3];
    const int n5 = N * NB_;
    const int T  = in_sizes[2] / n5;   // B = 1

    const int words64 = (N + 63) / 64;
    const int words32 = words64 * 2;

    float* out = (float*)d_out;

    // ws layout: [ offs E(int) | i_rec n5(f32) | zbits (T+MD)*words32(u32) | scnt T+MD(int) ]
    char* wsb = (char*)d_ws;
    int*          offs  = (int*)wsb;
    size_t off_b = (size_t)E * 4;
    float*        i_rec = (float*)(wsb + off_b);
    off_b += (size_t)n5 * 4;
    off_b = (off_b + 15) & ~(size_t)15;          // align zbits (u64 stores)
    unsigned int* zbits = (unsigned int*)(wsb + off_b);
    off_b += (size_t)(T + MD_) * words32 * 4;
    int*          scnt  = (int*)(wsb + off_b);

    int nblocks = 512;                // 2 blocks/CU co-resident; >= N threads
    dim3 gdim(nblocks), bdim(256);
    size_t shmem = (size_t)words32 * MD_ * sizeof(unsigned int);   // ~31 KB

    void* args[] = {
        (void*)&weights, (void*)&edge_basis, (void*)&ext_input,
        (void*)&decay, (void*)&current_factor, (void*)&gathered_g,
        (void*)&v_th, (void*)&v_reset, (void*)&normalizer, (void*)&t_ref,
        (void*)&exp_dt_k, (void*)&asc_amps, (void*)&syn_decay, (void*)&psc_initial,
        (void*)&pre_idx, (void*)&post_idx,
        (void*)&out, (void*)&offs, (void*)&i_rec, (void*)&zbits, (void*)&scnt,
        (void*)&N, (void*)&E, (void*)&T, (void*)&words32
    };
    hipLaunchCooperativeKernel((void*)v1_persistent, gdim, bdim, args,
                               (unsigned int)shmem, stream);
}

// Round 3
// 779.910 us; speedup vs baseline: 6.3504x; 6.3504x over previous
//
#include <hip/hip_runtime.h>

#define NB_ 5   // N_BASIS
#define MD_ 5   // MAX_DELAY

// ---------------------------------------------------------------------------
// CSR build (per launch): edges bucketed by window-slot key
//   key(e) = (MD-1 - d)*bitstride + n   where pre_idx[e] = d*N + n
// so at step t the slot's spike bit is  zbits[t*words32 + (key>>5)] >> (key&31).
// ---------------------------------------------------------------------------

__global__ __launch_bounds__(256) void hist_kernel(
    const int* __restrict__ pre_idx, int* __restrict__ cnt,
    int E, int N, int bitstride)
{
    int e = blockIdx.x * blockDim.x + threadIdx.x;
    if (e >= E) return;
    int pre = pre_idx[e];
    int d = pre / N;
    int n = pre - d * N;
    atomicAdd(&cnt[(MD_ - 1 - d) * bitstride + n], 1);
}

// Tile-wise exclusive scan. Each block scans SCAN_TILE=1024 items (4/thread),
// writes local-exclusive values to out[], and its tile total to partials[].
// Reused (with partials=nullptr, 1 block, in-place) to scan the partials.
#define SCAN_TILE 1024
__global__ __launch_bounds__(256) void scan_tiles_kernel(
    const int* __restrict__ in, int* __restrict__ out,
    int* __restrict__ partials, int NS)
{
    __shared__ int lds[256];
    int base = blockIdx.x * SCAN_TILE + threadIdx.x * 4;
    int v[4]; int s = 0;
    #pragma unroll
    for (int k = 0; k < 4; ++k) {
        int i = base + k;
        v[k] = (i < NS) ? in[i] : 0;
        s += v[k];
    }
    lds[threadIdx.x] = s;
    __syncthreads();
    int x = s;
    for (int off = 1; off < 256; off <<= 1) {
        int y = (threadIdx.x >= off) ? lds[threadIdx.x - off] : 0;
        __syncthreads();
        x += y;
        lds[threadIdx.x] = x;
        __syncthreads();
    }
    if (partials && threadIdx.x == 255) partials[blockIdx.x] = x;  // tile total
    int run = x - s;   // exclusive prefix of this thread's 4 items
    #pragma unroll
    for (int k = 0; k < 4; ++k) {
        int i = base + k;
        if (i < NS) out[i] = run;
        run += v[k];
    }
}

__global__ __launch_bounds__(256) void scan_addback_kernel(
    int* __restrict__ row_ptr, const int* __restrict__ partials, int NS)
{
    int i = blockIdx.x * blockDim.x + threadIdx.x;
    if (i < NS) row_ptr[i] += partials[i >> 10];   // tile = i / SCAN_TILE
}

// Scatter edge ids; atomicAdd turns row_ptr[s] into the END of row s,
// so row s = [ s? row_ptr[s-1] : 0 , row_ptr[s] ).
__global__ __launch_bounds__(256) void scatter_kernel(
    const int* __restrict__ pre_idx, int* __restrict__ row_ptr,
    int* __restrict__ sortedEid, int E, int N, int bitstride)
{
    int e = blockIdx.x * blockDim.x + threadIdx.x;
    if (e >= E) return;
    int pre = pre_idx[e];
    int d = pre / N;
    int n = pre - d * N;
    int key = (MD_ - 1 - d) * bitstride + n;
    int pos = atomicAdd(&row_ptr[key], 1);
    sortedEid[pos] = e;
}

// ---------------------------------------------------------------------------
// Per-step kernels
// ---------------------------------------------------------------------------

// One thread per window slot; only firing slots touch their edge list.
__global__ __launch_bounds__(256) void edge_csr_kernel(
    const unsigned int* __restrict__ zw,   // zbits + t*words32 (5-row window)
    const int* __restrict__ row_ptr,       // end-pointers (post-scatter)
    const int* __restrict__ sortedEid,
    const int* __restrict__ post_idx,
    const float* __restrict__ weights,
    const float* __restrict__ edge_basis,
    float* __restrict__ i_rec,
    int NS)
{
    int s = blockIdx.x * blockDim.x + threadIdx.x;
    if (s >= NS) return;
    unsigned int w = zw[s >> 5];
    if (!((w >> (s & 31)) & 1u)) return;
    int start = (s > 0) ? row_ptr[s - 1] : 0;
    int end   = row_ptr[s];
    for (int i = start; i < end; ++i) {
        int e = sortedEid[i];
        float wt = weights[e];
        int b = post_idx[e] * NB_;
        const float* bs = edge_basis + (size_t)e * NB_;
        #pragma unroll
        for (int k = 0; k < NB_; ++k)
            atomicAdd(&i_rec[b + k], wt * bs[k]);
    }
}

__global__ __launch_bounds__(256) void neuron_kernel(
    const float* __restrict__ x_t,        // ext_input + t*n5
    float*       __restrict__ psc,
    float*       __restrict__ i_rec,
    const float* __restrict__ syn_decay,
    const float* __restrict__ psc_initial,
    const float* __restrict__ decay,
    const float* __restrict__ current_factor,
    const float* __restrict__ gathered_g,
    const float* __restrict__ v_th,
    const float* __restrict__ v_reset,
    const float* __restrict__ normalizer,
    const float* __restrict__ t_ref,
    const float* __restrict__ exp_dt_k,   // (N,2)
    const float* __restrict__ asc_amps,   // (N,2)
    float*       __restrict__ v,
    float*       __restrict__ r,
    float*       __restrict__ asc,        // (N,2)
    const int*   __restrict__ scnt_t,     // scnt + t (5-slot window counts)
    int*         __restrict__ scnt_new,   // scnt + t + MD
    unsigned int* __restrict__ zrow_prev, // zbits + (t+MD-1)*words32
    unsigned int* __restrict__ zrow_new,  // zbits + (t+MD)*words32
    float*       __restrict__ out_t,      // out + t*N
    int N)
{
    int n = blockIdx.x * blockDim.x + threadIdx.x;
    bool has = (n < N);

    int scw = scnt_t[0] + scnt_t[1] + scnt_t[2] + scnt_t[3] + scnt_t[4];

    float z = 0.0f;
    if (has) {
        const float* x  = x_t + n * NB_;
        float*       pp = psc + n * NB_;
        float ic = 0.0f;
        if (scw > 0) {
            float* ir = i_rec + n * NB_;
            #pragma unroll
            for (int k = 0; k < NB_; ++k) {
                float pv = pp[k] * syn_decay[n * NB_ + k]
                         + (ir[k] + x[k]) * psc_initial[n * NB_ + k];
                pp[k] = pv;
                ir[k] = 0.0f;
                ic += pv;
            }
        } else {
            #pragma unroll
            for (int k = 0; k < NB_; ++k) {
                float pv = pp[k] * syn_decay[n * NB_ + k]
                         + (0.0f + x[k]) * psc_initial[n * NB_ + k];
                pp[k] = pv;
                ic += pv;
            }
        }

        // prev-step spike from the bit row (avoids an N-float array)
        unsigned int pw = zrow_prev[n >> 5];
        float pz = ((pw >> (n & 31)) & 1u) ? 1.0f : 0.0f;

        float a0 = exp_dt_k[2 * n]     * asc[2 * n]     + pz * asc_amps[2 * n];
        float a1 = exp_dt_k[2 * n + 1] * asc[2 * n + 1] + pz * asc_amps[2 * n + 1];
        asc[2 * n]     = a0;
        asc[2 * n + 1] = a1;

        float c1 = ic + (a0 + a1) + gathered_g[n];
        float nv = decay[n] * v[n] + current_factor[n] * c1;
        if (pz > 0.5f) nv = v_reset[n];

        float vsc = (nv - v_th[n]) / normalizer[n];
        z = (vsc > 0.0f) ? 1.0f : 0.0f;
        float rr = r[n];
        if (rr > 0.0f) z = 0.0f;

        r[n] = fmaxf(rr + z * t_ref[n] - 1.0f, 0.0f);   // DT = 1.0
        v[n] = nv;
        out_t[n] = z;
    }

    // bit-pack this step's spikes: one u64 store per wave
    unsigned long long m = __ballot(z != 0.0f);
    int wv = (blockIdx.x * blockDim.x + threadIdx.x) >> 6;
    if ((threadIdx.x & 63) == 0 && (wv << 6) < N) {
        *(unsigned long long*)(zrow_new + (wv << 1)) = m;
        if (m) atomicAdd(scnt_new, __popcll(m));
    }
}

// ---------------------------------------------------------------------------
// Launcher
// ---------------------------------------------------------------------------

extern "C" void kernel_launch(void* const* d_in, const int* in_sizes, int n_in,
                              void* d_out, int out_size, void* d_ws, size_t ws_size,
                              hipStream_t stream)
{
    const float* weights        = (const float*)d_in[0];
    const float* edge_basis     = (const float*)d_in[1];
    const float* ext_input      = (const float*)d_in[2];
    const float* decay          = (const float*)d_in[3];
    const float* current_factor = (const float*)d_in[4];
    const float* gathered_g     = (const float*)d_in[5];
    const float* v_th           = (const float*)d_in[6];
    const float* v_reset        = (const float*)d_in[7];
    const float* normalizer     = (const float*)d_in[8];
    const float* t_ref          = (const float*)d_in[9];
    const float* exp_dt_k       = (const float*)d_in[10];
    const float* asc_amps       = (const float*)d_in[11];
    const float* syn_decay      = (const float*)d_in[12];
    const float* psc_initial    = (const float*)d_in[13];
    const int*   pre_idx        = (const int*)d_in[14];
    const int*   post_idx       = (const int*)d_in[15];

    const int E  = in_sizes[0];
    const int N  = in_sizes[3];
    const int n5 = N * NB_;
    const int T  = in_sizes[2] / n5;          // B = 1

    const int words64   = (N + 63) / 64;      // 782
    const int words32   = words64 * 2;        // 1564
    const int bitstride = words32 * 32;       // 50048
    const int NS        = MD_ * bitstride;    // 250240 slots

    float* out = (float*)d_out;

    // ---- workspace layout --------------------------------------------------
    // zero group (one memset): [cnt NS | i_rec n5 | psc n5 | r N | asc 2N |
    //                           scnt T+MD | zbits head MD*words32]
    char* wsb = (char*)d_ws;
    size_t o = 0;
    int*   cnt    = (int*)(wsb + o);  o += (size_t)NS * 4;
    float* i_rec  = (float*)(wsb + o); o += (size_t)n5 * 4;
    float* psc    = (float*)(wsb + o); o += (size_t)n5 * 4;
    float* r      = (float*)(wsb + o); o += (size_t)N * 4;
    float* asc    = (float*)(wsb + o); o += (size_t)2 * N * 4;
    int*   scnt   = (int*)(wsb + o);  o += (size_t)(T + MD_) * 4;
    o = (o + 15) & ~(size_t)15;
    unsigned int* zbits = (unsigned int*)(wsb + o);
    size_t zero_bytes = o + (size_t)MD_ * words32 * 4;   // through zbits head
    o += (size_t)(T + MD_) * words32 * 4;
    o = (o + 15) & ~(size_t)15;
    float* v       = (float*)(wsb + o); o += (size_t)N * 4;
    int*   row_ptr = (int*)(wsb + o);   o += (size_t)(NS + 1) * 4;
    int*   sortedEid = (int*)(wsb + o); o += (size_t)E * 4;
    int*   partials  = (int*)(wsb + o); o += 256 * 4;

    // ---- setup (every launch: graph replays everything) --------------------
    hipMemsetAsync(d_ws, 0, zero_bytes, stream);
    hipMemcpyAsync(v, v_reset, (size_t)N * 4, hipMemcpyDeviceToDevice, stream);

    const int eblk = (E + 255) / 256;
    hist_kernel<<<eblk, 256, 0, stream>>>(pre_idx, cnt, E, N, bitstride);

    const int ntilesA = (NS + SCAN_TILE - 1) / SCAN_TILE;   // 245
    scan_tiles_kernel<<<ntilesA, 256, 0, stream>>>(cnt, row_ptr, partials, NS);
    scan_tiles_kernel<<<1, 256, 0, stream>>>(partials, partials, (int*)nullptr, ntilesA);
    scan_addback_kernel<<<(NS + 255) / 256, 256, 0, stream>>>(row_ptr, partials, NS);
    scatter_kernel<<<eblk, 256, 0, stream>>>(pre_idx, row_ptr, sortedEid, E, N, bitstride);

    // ---- time loop ----------------------------------------------------------
    const int sblk = (NS + 255) / 256;   // 978
    const int nblk = (N + 255) / 256;    // 196
    for (int t = 0; t < T; ++t) {
        edge_csr_kernel<<<sblk, 256, 0, stream>>>(
            zbits + (size_t)t * words32,
            row_ptr, sortedEid, post_idx, weights, edge_basis, i_rec, NS);

        neuron_kernel<<<nblk, 256, 0, stream>>>(
            ext_input + (size_t)t * n5,
            psc, i_rec, syn_decay, psc_initial,
            decay, current_factor, gathered_g,
            v_th, v_reset, normalizer, t_ref,
            exp_dt_k, asc_amps,
            v, r, asc,
            scnt + t, scnt + t + MD_,
            zbits + (size_t)(t + MD_ - 1) * words32,
            zbits + (size_t)(t + MD_) * words32,
            out + (size_t)t * N,
            N);
    }
}

// Round 4
// 778.078 us; speedup vs baseline: 6.3653x; 1.0024x over previous
//
#include <hip/hip_runtime.h>

#define NB_ 5   // N_BASIS
#define MD_ 5   // MAX_DELAY

// ---------------------------------------------------------------------------
// CSR build (per launch): edges bucketed by window-slot key
//   key(e) = (MD-1 - d)*bitstride + n   where pre_idx[e] = d*N + n
// so at step t the slot's spike bit is  zbits[t*words32 + (key>>5)] >> (key&31).
// ---------------------------------------------------------------------------

__global__ __launch_bounds__(256) void hist_kernel(
    const int* __restrict__ pre_idx, int* __restrict__ cnt,
    int E, int N, int bitstride)
{
    int e = blockIdx.x * blockDim.x + threadIdx.x;
    if (e >= E) return;
    int pre = pre_idx[e];
    int d = pre / N;
    int n = pre - d * N;
    atomicAdd(&cnt[(MD_ - 1 - d) * bitstride + n], 1);
}

// Tile-wise exclusive scan. Each block scans SCAN_TILE=1024 items (4/thread),
// writes local-exclusive values to out[], and its tile total to partials[].
// Reused (with partials=nullptr, 1 block, in-place) to scan the partials.
#define SCAN_TILE 1024
__global__ __launch_bounds__(256) void scan_tiles_kernel(
    const int* __restrict__ in, int* __restrict__ out,
    int* __restrict__ partials, int NS)
{
    __shared__ int lds[256];
    int base = blockIdx.x * SCAN_TILE + threadIdx.x * 4;
    int v[4]; int s = 0;
    #pragma unroll
    for (int k = 0; k < 4; ++k) {
        int i = base + k;
        v[k] = (i < NS) ? in[i] : 0;
        s += v[k];
    }
    lds[threadIdx.x] = s;
    __syncthreads();
    int x = s;
    for (int off = 1; off < 256; off <<= 1) {
        int y = (threadIdx.x >= off) ? lds[threadIdx.x - off] : 0;
        __syncthreads();
        x += y;
        lds[threadIdx.x] = x;
        __syncthreads();
    }
    if (partials && threadIdx.x == 255) partials[blockIdx.x] = x;  // tile total
    int run = x - s;   // exclusive prefix of this thread's 4 items
    #pragma unroll
    for (int k = 0; k < 4; ++k) {
        int i = base + k;
        if (i < NS) out[i] = run;
        run += v[k];
    }
}

__global__ __launch_bounds__(256) void scan_addback_kernel(
    int* __restrict__ row_ptr, const int* __restrict__ partials, int NS)
{
    int i = blockIdx.x * blockDim.x + threadIdx.x;
    if (i < NS) row_ptr[i] += partials[i >> 10];   // tile = i / SCAN_TILE
}

// Scatter edge ids; atomicAdd turns row_ptr[s] into the END of row s,
// so row s = [ s? row_ptr[s-1] : 0 , row_ptr[s] ).
__global__ __launch_bounds__(256) void scatter_kernel(
    const int* __restrict__ pre_idx, int* __restrict__ row_ptr,
    int* __restrict__ sortedEid, int E, int N, int bitstride)
{
    int e = blockIdx.x * blockDim.x + threadIdx.x;
    if (e >= E) return;
    int pre = pre_idx[e];
    int d = pre / N;
    int n = pre - d * N;
    int key = (MD_ - 1 - d) * bitstride + n;
    int pos = atomicAdd(&row_ptr[key], 1);
    sortedEid[pos] = e;
}

// ---------------------------------------------------------------------------
// Per-step kernels
// ---------------------------------------------------------------------------

// One thread per window slot; only firing slots touch their edge list.
__global__ __launch_bounds__(256) void edge_csr_kernel(
    const unsigned int* __restrict__ zw,   // zbits + t*words32 (5-row window)
    const int* __restrict__ row_ptr,       // end-pointers (post-scatter)
    const int* __restrict__ sortedEid,
    const int* __restrict__ post_idx,
    const float* __restrict__ weights,
    const float* __restrict__ edge_basis,
    float* __restrict__ i_rec,
    int NS)
{
    int s = blockIdx.x * blockDim.x + threadIdx.x;
    if (s >= NS) return;
    unsigned int w = zw[s >> 5];
    if (!((w >> (s & 31)) & 1u)) return;
    int start = (s > 0) ? row_ptr[s - 1] : 0;
    int end   = row_ptr[s];
    for (int i = start; i < end; ++i) {
        int e = sortedEid[i];
        float wt = weights[e];
        int b = post_idx[e] * NB_;
        const float* bs = edge_basis + (size_t)e * NB_;
        #pragma unroll
        for (int k = 0; k < NB_; ++k)
            atomicAdd(&i_rec[b + k], wt * bs[k]);
    }
}

__global__ __launch_bounds__(256) void neuron_kernel(
    const float* __restrict__ x_t,        // ext_input + t*n5
    float*       __restrict__ psc,
    float*       __restrict__ i_rec,
    const float* __restrict__ syn_decay,
    const float* __restrict__ psc_initial,
    const float* __restrict__ decay,
    const float* __restrict__ current_factor,
    const float* __restrict__ gathered_g,
    const float* __restrict__ v_th,
    const float* __restrict__ v_reset,
    const float* __restrict__ normalizer,
    const float* __restrict__ t_ref,
    const float* __restrict__ exp_dt_k,   // (N,2)
    const float* __restrict__ asc_amps,   // (N,2)
    float*       __restrict__ v,
    float*       __restrict__ r,
    float*       __restrict__ asc,        // (N,2)
    const int*   __restrict__ scnt_t,     // scnt + t (5-slot window counts)
    int*         __restrict__ scnt_new,   // scnt + t + MD
    unsigned int* __restrict__ zrow_prev, // zbits + (t+MD-1)*words32
    unsigned int* __restrict__ zrow_new,  // zbits + (t+MD)*words32
    float*       __restrict__ out_t,      // out + t*N
    int N)
{
    int n = blockIdx.x * blockDim.x + threadIdx.x;
    bool has = (n < N);

    int scw = scnt_t[0] + scnt_t[1] + scnt_t[2] + scnt_t[3] + scnt_t[4];

    float z = 0.0f;
    if (has) {
        const float* x  = x_t + n * NB_;
        float*       pp = psc + n * NB_;
        float ic = 0.0f;
        if (scw > 0) {
            float* ir = i_rec + n * NB_;
            #pragma unroll
            for (int k = 0; k < NB_; ++k) {
                float pv = pp[k] * syn_decay[n * NB_ + k]
                         + (ir[k] + x[k]) * psc_initial[n * NB_ + k];
                pp[k] = pv;
                ir[k] = 0.0f;
                ic += pv;
            }
        } else {
            #pragma unroll
            for (int k = 0; k < NB_; ++k) {
                float pv = pp[k] * syn_decay[n * NB_ + k]
                         + (0.0f + x[k]) * psc_initial[n * NB_ + k];
                pp[k] = pv;
                ic += pv;
            }
        }

        // prev-step spike from the bit row (avoids an N-float array)
        unsigned int pw = zrow_prev[n >> 5];
        float pz = ((pw >> (n & 31)) & 1u) ? 1.0f : 0.0f;

        float a0 = exp_dt_k[2 * n]     * asc[2 * n]     + pz * asc_amps[2 * n];
        float a1 = exp_dt_k[2 * n + 1] * asc[2 * n + 1] + pz * asc_amps[2 * n + 1];
        asc[2 * n]     = a0;
        asc[2 * n + 1] = a1;

        float c1 = ic + (a0 + a1) + gathered_g[n];
        float nv = decay[n] * v[n] + current_factor[n] * c1;
        if (pz > 0.5f) nv = v_reset[n];

        float vsc = (nv - v_th[n]) / normalizer[n];
        z = (vsc > 0.0f) ? 1.0f : 0.0f;
        float rr = r[n];
        if (rr > 0.0f) z = 0.0f;

        r[n] = fmaxf(rr + z * t_ref[n] - 1.0f, 0.0f);   // DT = 1.0
        v[n] = nv;
        out_t[n] = z;
    }

    // bit-pack this step's spikes: one u64 store per wave
    unsigned long long m = __ballot(z != 0.0f);
    int wv = (blockIdx.x * blockDim.x + threadIdx.x) >> 6;
    if ((threadIdx.x & 63) == 0 && (wv << 6) < N) {
        *(unsigned long long*)(zrow_new + (wv << 1)) = m;
        if (m) atomicAdd(scnt_new, __popcll(m));
    }
}

// ---------------------------------------------------------------------------
// Launcher
// ---------------------------------------------------------------------------

extern "C" void kernel_launch(void* const* d_in, const int* in_sizes, int n_in,
                              void* d_out, int out_size, void* d_ws, size_t ws_size,
                              hipStream_t stream)
{
    const float* weights        = (const float*)d_in[0];
    const float* edge_basis     = (const float*)d_in[1];
    const float* ext_input      = (const float*)d_in[2];
    const float* decay          = (const float*)d_in[3];
    const float* current_factor = (const float*)d_in[4];
    const float* gathered_g     = (const float*)d_in[5];
    const float* v_th           = (const float*)d_in[6];
    const float* v_reset        = (const float*)d_in[7];
    const float* normalizer     = (const float*)d_in[8];
    const float* t_ref          = (const float*)d_in[9];
    const float* exp_dt_k       = (const float*)d_in[10];
    const float* asc_amps       = (const float*)d_in[11];
    const float* syn_decay      = (const float*)d_in[12];
    const float* psc_initial    = (const float*)d_in[13];
    const int*   pre_idx        = (const int*)d_in[14];
    const int*   post_idx       = (const int*)d_in[15];

    const int E  = in_sizes[0];
    const int N  = in_sizes[3];
    const int n5 = N * NB_;
    const int T  = in_sizes[2] / n5;          // B = 1

    const int words64   = (N + 63) / 64;      // 782
    const int words32   = words64 * 2;        // 1564
    const int bitstride = words32 * 32;       // 50048
    const int NS        = MD_ * bitstride;    // 250240 slots

    float* out = (float*)d_out;

    // ---- workspace layout --------------------------------------------------
    // zero group (one memset): [cnt NS | i_rec n5 | psc n5 | r N | asc 2N |
    //                           scnt T+MD | zbits head MD*words32]
    char* wsb = (char*)d_ws;
    size_t o = 0;
    int*   cnt    = (int*)(wsb + o);  o += (size_t)NS * 4;
    float* i_rec  = (float*)(wsb + o); o += (size_t)n5 * 4;
    float* psc    = (float*)(wsb + o); o += (size_t)n5 * 4;
    float* r      = (float*)(wsb + o); o += (size_t)N * 4;
    float* asc    = (float*)(wsb + o); o += (size_t)2 * N * 4;
    int*   scnt   = (int*)(wsb + o);  o += (size_t)(T + MD_) * 4;
    o = (o + 15) & ~(size_t)15;
    unsigned int* zbits = (unsigned int*)(wsb + o);
    size_t zero_bytes = o + (size_t)MD_ * words32 * 4;   // through zbits head
    o += (size_t)(T + MD_) * words32 * 4;
    o = (o + 15) & ~(size_t)15;
    float* v       = (float*)(wsb + o); o += (size_t)N * 4;
    int*   row_ptr = (int*)(wsb + o);   o += (size_t)(NS + 1) * 4;
    int*   sortedEid = (int*)(wsb + o); o += (size_t)E * 4;
    int*   partials  = (int*)(wsb + o); o += 256 * 4;

    // ---- setup (every launch: graph replays everything) --------------------
    hipMemsetAsync(d_ws, 0, zero_bytes, stream);
    hipMemcpyAsync(v, v_reset, (size_t)N * 4, hipMemcpyDeviceToDevice, stream);

    const int eblk = (E + 255) / 256;
    hist_kernel<<<eblk, 256, 0, stream>>>(pre_idx, cnt, E, N, bitstride);

    const int ntilesA = (NS + SCAN_TILE - 1) / SCAN_TILE;   // 245
    scan_tiles_kernel<<<ntilesA, 256, 0, stream>>>(cnt, row_ptr, partials, NS);
    scan_tiles_kernel<<<1, 256, 0, stream>>>(partials, partials, (int*)nullptr, ntilesA);
    scan_addback_kernel<<<(NS + 255) / 256, 256, 0, stream>>>(row_ptr, partials, NS);
    scatter_kernel<<<eblk, 256, 0, stream>>>(pre_idx, row_ptr, sortedEid, E, N, bitstride);

    // ---- time loop ----------------------------------------------------------
    const int sblk = (NS + 255) / 256;   // 978
    const int nblk = (N + 255) / 256;    // 196
    for (int t = 0; t < T; ++t) {
        edge_csr_kernel<<<sblk, 256, 0, stream>>>(
            zbits + (size_t)t * words32,
            row_ptr, sortedEid, post_idx, weights, edge_basis, i_rec, NS);

        neuron_kernel<<<nblk, 256, 0, stream>>>(
            ext_input + (size_t)t * n5,
            psc, i_rec, syn_decay, psc_initial,
            decay, current_factor, gathered_g,
            v_th, v_reset, normalizer, t_ref,
            exp_dt_k, asc_amps,
            v, r, asc,
            scnt + t, scnt + t + MD_,
            zbits + (size_t)(t + MD_ - 1) * words32,
            zbits + (size_t)(t + MD_) * words32,
            out + (size_t)t * N,
            N);
    }
}